// Round 1
// 105.234 us; speedup vs baseline: 1.0071x; 1.0071x over previous
//
#include <hip/hip_runtime.h>

// ---------------------------------------------------------------------------
// NeuralTheoremProver depth-1 score, MI355X.  Round 5.
//
//   score[b] = (1/E) * sum_z S1[b,z] * s2[b,z]
//   S1[b,z]  = sum_r sqrt(max(C1[b,r] + Gz[z,r] - 2*hz[b,z], 0))
//   s2[b,z]  = sqrt(max(G2[z] + C2[b] - 2*zt[b,z], 0))
//   hz = H @ E^T, zt = T @ E^T  -> bf16 MFMA 16x16x32
//
// R5 changes vs R4 (R4 post-mortem: both kernels < 42us fill dispatches;
// ntp_main is VALU-issue-bound: 4 full-rate + 1 max ops per sqrt ~doubles
// the trans-pipe floor of 6.8us):
//  * Inner S1 loop rewritten on float2 -> v_pk_add_f32 packed adds:
//    3 pk-ops / 2 elements instead of 8 scalar adds + 2 max.
//  * fmax(x,0) dropped: sqrt(|x|) -- abs is a free VOP3 input modifier on
//    v_sqrt_f32. sq1/sq2 are >= 0 up to rounding (typ ~250), error << bf16
//    MFMA noise already accepted by the checker.
//  * ntp_pre grid reordered batch-blocks-FIRST so the 64 gather-latency
//    blocks overlap the 512 entity blocks instead of forming an idle tail.
// ---------------------------------------------------------------------------

typedef __attribute__((ext_vector_type(8))) short short8;   // 8 x bf16 (4 VGPR)
typedef __attribute__((ext_vector_type(4))) float f32x4;
typedef __attribute__((ext_vector_type(2))) float f32x2;

__device__ inline unsigned short f2bf(float f) {            // RNE fp32->bf16
  unsigned int u = __float_as_uint(f);
  u += 0x7fffu + ((u >> 16) & 1u);
  return (unsigned short)(u >> 16);
}

// Fused precompute. Block = 256 threads = 16 rows x 16 r-lanes.
// Blocks [0, nBB)  : batch rows   -> Hbf, Tbf, C1, C2, out=0   (gathers: first!)
// Blocks [nBB, end): entity rows  -> Ebf, Gz, G2
__global__ __launch_bounds__(256) void ntp_pre(
    const float* __restrict__ Etab, const float* __restrict__ rules,
    const int* __restrict__ head, const int* __restrict__ tail,
    const int* __restrict__ qrelp, unsigned short* __restrict__ Ebf,
    unsigned short* __restrict__ Hbf, unsigned short* __restrict__ Tbf,
    float* __restrict__ Gz, float* __restrict__ G2, float* __restrict__ C1,
    float* __restrict__ C2, float* __restrict__ out, int nBB) {
  __shared__ __align__(16) float sR[16][132];   // rules, +4 pad -> 2-way alias
  const int tid = threadIdx.x;
  const int gl = tid >> 4;          // row within this block's 16-row tile
  const int r  = tid & 15;          // rule index
  const int qrel = qrelp[0];

  // Stage all 16 rule rows: 512 f32x4, 2 per thread.
#pragma unroll
  for (int rep = 0; rep < 2; ++rep) {
    int idx = tid + rep * 256;                  // f32x4 index
    int row = idx >> 5, colv = idx & 31;
    *reinterpret_cast<f32x4*>(&sR[row][colv * 4]) =
        *reinterpret_cast<const f32x4*>(rules + (size_t)row * 128 + colv * 4);
  }
  __syncthreads();

  if ((int)blockIdx.x >= nBB) {
    const int z = (blockIdx.x - nBB) * 16 + gl;
    const float* ez = Etab + (size_t)z * 128;
    float rz = 0.f, zz = 0.f, rr = 0.f;
#pragma unroll
    for (int k = 0; k < 128; k += 4) {
      f32x4 ev = *reinterpret_cast<const f32x4*>(ez + k);
      f32x4 rv = *reinterpret_cast<const f32x4*>(&sR[r][k]);
#pragma unroll
      for (int j = 0; j < 4; ++j) {
        rz += ev[j] * rv[j];
        zz += ev[j] * ev[j];
        rr += rv[j] * rv[j];
      }
    }
    Gz[(size_t)z * 16 + r] = zz - 2.f * rz;                 // zz - 2 z.r
    if (r == qrel) G2[z] = zz + 2.f * rz + rr;              // zz + 2 z.q + qq
    const float* src = ez + r * 8;
    short8 o;
#pragma unroll
    for (int j = 0; j < 8; ++j) o[j] = (short)f2bf(src[j]);
    *reinterpret_cast<short8*>(Ebf + (size_t)z * 128 + r * 8) = o;
  } else {
    const int b = blockIdx.x * 16 + gl;
    const int hi = head[b], ti = tail[b];
    const float* hp = Etab + (size_t)hi * 128;
    const float* tp = Etab + (size_t)ti * 128;
    float hr = 0.f, tq = 0.f, hh = 0.f, tt = 0.f, rr = 0.f;
#pragma unroll
    for (int k = 0; k < 128; k += 4) {
      f32x4 hv = *reinterpret_cast<const f32x4*>(hp + k);
      f32x4 tv = *reinterpret_cast<const f32x4*>(tp + k);
      f32x4 rv = *reinterpret_cast<const f32x4*>(&sR[r][k]);
#pragma unroll
      for (int j = 0; j < 4; ++j) {
        hr += hv[j] * rv[j];
        tq += tv[j] * rv[j];
        hh += hv[j] * hv[j];
        tt += tv[j] * tv[j];
        rr += rv[j] * rv[j];
      }
    }
    C1[(size_t)b * 16 + r] = hh + rr + 2.f * hr;            // hh + rr + 2 h.r
    if (r == qrel) C2[b] = tt - 2.f * tq;                   // tt - 2 q.t
    if (r == 0) out[b] = 0.f;
    short8 oh, ot;
    const float* hsrc = hp + r * 8;
    const float* tsrc = tp + r * 8;
#pragma unroll
    for (int j = 0; j < 8; ++j) {
      oh[j] = (short)f2bf(hsrc[j]);
      ot[j] = (short)f2bf(tsrc[j]);
    }
    *reinterpret_cast<short8*>(Hbf + (size_t)b * 128 + r * 8) = oh;
    *reinterpret_cast<short8*>(Tbf + (size_t)b * 128 + r * 8) = ot;
  }
}

// Main fused kernel. Block = 32 b x 64 z (2 chunks of 32 z).
// Stage-once to LDS, single barrier, barrier-free compute from LDS.
// 4 waves: wave w -> b-half (w>>1), z-half (w&1); each owns a 16x16 MFMA tile.
// MFMA layouts (m89/m92-verified):
//   A[m=lane&15][k=quad*8+j], B[k=quad*8+j][n=lane&15], D[m=quad*4+reg][n=lane&15]
__global__ __launch_bounds__(256, 4) void ntp_main(
    const unsigned short* __restrict__ Ebf, const unsigned short* __restrict__ Hbf,
    const unsigned short* __restrict__ Tbf, const float* __restrict__ Gz,
    const float* __restrict__ G2, const float* __restrict__ C1,
    const float* __restrict__ C2, float* __restrict__ out, int Ecount) {
  // Pads: sEz row 136 shorts (272B, bank shift 4/row -> 2-way alias = free),
  // sGz row 20 f32 (80B -> 2-way), sC1 row 20 f32 (reads are broadcasts).
  __shared__ __align__(16) unsigned short sEz[64][136];   // 17408 B
  __shared__ __align__(16) float sGz[64][20];             //  5120 B
  __shared__ __align__(16) float sG2[64];                 //   256 B
  __shared__ __align__(16) float sC1[32][20];             //  2560 B

  const int tid   = threadIdx.x;
  const int lane  = tid & 63, wave = tid >> 6;
  const int bhalf = wave >> 1, zhalf = wave & 1;
  const int quad  = lane >> 4, lm = lane & 15;
  const int b_base = blockIdx.x * 32;
  const int z_base = blockIdx.y * 64;

  // ---- one-shot staging (coalesced 16B/lane) ----
#pragma unroll
  for (int rep = 0; rep < 4; ++rep) {           // Ez: 64 rows x 256 B
    int c = tid + rep * 256;
    int row = c >> 4, col = c & 15;
    *reinterpret_cast<short8*>(&sEz[row][col * 8]) =
        *reinterpret_cast<const short8*>(Ebf + (size_t)(z_base + row) * 128 + col * 8);
  }
  {                                             // Gz: 64 rows x 64 B
    int row = tid >> 2, colv = tid & 3;
    *reinterpret_cast<f32x4*>(&sGz[row][colv * 4]) =
        *reinterpret_cast<const f32x4*>(Gz + (size_t)(z_base + row) * 16 + colv * 4);
  }
  if (tid < 64) sG2[tid] = G2[z_base + tid];
  if (tid < 128) {                              // C1: 32 rows x 64 B
    int row = tid >> 2, colv = tid & 3;
    *reinterpret_cast<f32x4*>(&sC1[row][colv * 4]) =
        *reinterpret_cast<const f32x4*>(&C1[(size_t)(b_base + row) * 16 + colv * 4]);
  }

  // A-fragments (H and T rows for this wave's 16 b's) register-resident.
  short8 hfrag[4], tfrag[4];
  {
    const size_t brow = (size_t)(b_base + bhalf * 16 + lm) * 128 + quad * 8;
    const unsigned short* hp = Hbf + brow;
    const unsigned short* tp = Tbf + brow;
#pragma unroll
    for (int k4 = 0; k4 < 4; ++k4) {
      hfrag[k4] = *reinterpret_cast<const short8*>(hp + k4 * 32);
      tfrag[k4] = *reinterpret_cast<const short8*>(tp + k4 * 32);
    }
  }

  // C2 for this lane's 4 b's -> registers (independent of lm).
  float c2v[4];
#pragma unroll
  for (int reg = 0; reg < 4; ++reg)
    c2v[reg] = C2[b_base + bhalf * 16 + quad * 4 + reg];

  __syncthreads();   // staging complete; no further barriers.

  const int z_loc = zhalf * 16 + lm;
  const float scale = 1.0f / (float)Ecount;
  f32x4 acc_out = {0.f, 0.f, 0.f, 0.f};

#pragma unroll
  for (int c = 0; c < 2; ++c) {
    const int zr = c * 32 + z_loc;              // LDS row for this lane's z

    f32x4 acc_hz = {0.f, 0.f, 0.f, 0.f};
    f32x4 acc_zt = {0.f, 0.f, 0.f, 0.f};
#pragma unroll
    for (int k4 = 0; k4 < 4; ++k4) {
      short8 ef = *reinterpret_cast<const short8*>(&sEz[zr][k4 * 32 + quad * 8]);
      acc_hz = __builtin_amdgcn_mfma_f32_16x16x32_bf16(hfrag[k4], ef, acc_hz, 0, 0, 0);
      acc_zt = __builtin_amdgcn_mfma_f32_16x16x32_bf16(tfrag[k4], ef, acc_zt, 0, 0, 0);
    }

    // Gz pairs for this z, register-resident as float2 for packed adds.
    f32x2 grp[8];
#pragma unroll
    for (int i = 0; i < 4; ++i) {
      f32x4 g = *reinterpret_cast<const f32x4*>(&sGz[zr][i * 4]);
      grp[2 * i]     = __builtin_shufflevector(g, g, 0, 1);
      grp[2 * i + 1] = __builtin_shufflevector(g, g, 2, 3);
    }
    const float g2v = sG2[zr];

#pragma unroll
    for (int reg = 0; reg < 4; ++reg) {
      const int b_loc = bhalf * 16 + quad * 4 + reg;
      const float zt = acc_zt[reg];
      const float sq2 = g2v + c2v[reg] - 2.f * zt;
      const float s2 = __builtin_amdgcn_sqrtf(__builtin_fabsf(sq2));
      const float m2hz = -2.f * acc_hz[reg];
      const f32x2 m2 = {m2hz, m2hz};
      f32x2 s1p = {0.f, 0.f};
#pragma unroll
      for (int i = 0; i < 4; ++i) {
        f32x4 cq = *reinterpret_cast<const f32x4*>(&sC1[b_loc][i * 4]);  // bcast
        f32x2 a0 = (__builtin_shufflevector(cq, cq, 0, 1) + grp[2 * i]) + m2;
        f32x2 a1 = (__builtin_shufflevector(cq, cq, 2, 3) + grp[2 * i + 1]) + m2;
        f32x2 rt0, rt1;
        rt0.x = __builtin_amdgcn_sqrtf(__builtin_fabsf(a0.x));
        rt0.y = __builtin_amdgcn_sqrtf(__builtin_fabsf(a0.y));
        rt1.x = __builtin_amdgcn_sqrtf(__builtin_fabsf(a1.x));
        rt1.y = __builtin_amdgcn_sqrtf(__builtin_fabsf(a1.y));
        s1p += rt0 + rt1;                       // v_pk_add_f32
      }
      acc_out[reg] += (s1p.x + s1p.y) * s2;     // (-S1)*(-s2) = S1*s2
    }
  }

  // Reduce over the 16 n-lanes, then one atomic per (b, z-block).
#pragma unroll
  for (int reg = 0; reg < 4; ++reg) {
    float v = acc_out[reg];
    v += __shfl_xor(v, 1, 16);
    v += __shfl_xor(v, 2, 16);
    v += __shfl_xor(v, 4, 16);
    v += __shfl_xor(v, 8, 16);
    if (lm == 0)
      atomicAdd(&out[b_base + bhalf * 16 + quad * 4 + reg], v * scale);
  }
}

extern "C" void kernel_launch(void* const* d_in, const int* in_sizes, int n_in,
                              void* d_out, int out_size, void* d_ws, size_t ws_size,
                              hipStream_t stream) {
  const int* head  = (const int*)d_in[0];
  const int* tail  = (const int*)d_in[1];
  const int* qrel  = (const int*)d_in[2];
  // d_in[3] = depth (unused at depth==1 closed form)
  const float* Etab  = (const float*)d_in[4];
  const float* rules = (const float*)d_in[5];
  const int B = in_sizes[0];
  const int E = in_sizes[4] / 128;
  float* out = (float*)d_out;

  char* ws = (char*)d_ws;
  unsigned short* Ebf = (unsigned short*)ws;                       // E*128*2 B
  unsigned short* Hbf = (unsigned short*)(ws + (size_t)E * 256);   // B*128*2 B
  unsigned short* Tbf = Hbf + (size_t)B * 128;                     // B*128*2 B
  float* Gz = (float*)(ws + (size_t)E * 256 + (size_t)B * 512);    // E*16*4 B
  float* G2 = Gz + (size_t)E * 16;                                 // E*4 B
  float* C1 = G2 + E;                                              // B*16*4 B
  float* C2 = C1 + (size_t)B * 16;                                 // B*4 B

  const int nEB = E / 16;                                          // 512
  const int nBB = B / 16;                                          // 64
  ntp_pre<<<nEB + nBB, 256, 0, stream>>>(Etab, rules, head, tail, qrel, Ebf,
                                         Hbf, Tbf, Gz, G2, C1, C2, out, nBB);
  ntp_main<<<dim3(B / 32, E / 64), 256, 0, stream>>>(Ebf, Hbf, Tbf, Gz, G2, C1,
                                                     C2, out, E);
}

// Round 2
// 104.667 us; speedup vs baseline: 1.0126x; 1.0054x over previous
//
#include <hip/hip_runtime.h>

// ---------------------------------------------------------------------------
// NeuralTheoremProver depth-1 score, MI355X.  Round 6.
//
//   score[b] = (1/E) * sum_z S1[b,z] * s2[b,z]
//   S1[b,z]  = sum_r sqrt(max(C1[b,r] + Gz[z,r] - 2*hz[b,z], 0))
//   s2[b,z]  = sqrt(max(G2[z] + C2[b] - 2*zt[b,z], 0))
//   hz = H @ E^T, zt = T @ E^T  -> bf16 MFMA 16x16x32
//
// R6 changes vs R5 (R5 post-mortem: -0.75us only; timed region is dominated
// by fixed 256MiB harness poison fills (~42.7us each, 78-80% HBM peak); our
// kernels' residual floor is LDS-port (~7.6us) and trans (~6.8us), with the
// 32 sC1 b128 reads/wave-block re-read per z-chunk the largest LDS term):
//  * Loop order inverted to reg-outer / chunk-inner: both chunks' MFMAs are
//    hoisted up front (acc_hz[2]/acc_zt[2], frags die after -> regs reused),
//    Gz pairs + G2 for BOTH chunks register-resident, sC1 row read ONCE per
//    reg (16 b128/wave-block instead of 32; hot-loop LDS issue -30%).
//  * s1 accumulation split into two f32x2 chains (breaks 4-cyc pk-add dep).
//  * Everything else (staging, pads, ntp_pre batch-first) unchanged.
// ---------------------------------------------------------------------------

typedef __attribute__((ext_vector_type(8))) short short8;   // 8 x bf16 (4 VGPR)
typedef __attribute__((ext_vector_type(4))) float f32x4;
typedef __attribute__((ext_vector_type(2))) float f32x2;

__device__ inline unsigned short f2bf(float f) {            // RNE fp32->bf16
  unsigned int u = __float_as_uint(f);
  u += 0x7fffu + ((u >> 16) & 1u);
  return (unsigned short)(u >> 16);
}

// Fused precompute. Block = 256 threads = 16 rows x 16 r-lanes.
// Blocks [0, nBB)  : batch rows   -> Hbf, Tbf, C1, C2, out=0   (gathers: first!)
// Blocks [nBB, end): entity rows  -> Ebf, Gz, G2
__global__ __launch_bounds__(256) void ntp_pre(
    const float* __restrict__ Etab, const float* __restrict__ rules,
    const int* __restrict__ head, const int* __restrict__ tail,
    const int* __restrict__ qrelp, unsigned short* __restrict__ Ebf,
    unsigned short* __restrict__ Hbf, unsigned short* __restrict__ Tbf,
    float* __restrict__ Gz, float* __restrict__ G2, float* __restrict__ C1,
    float* __restrict__ C2, float* __restrict__ out, int nBB) {
  __shared__ __align__(16) float sR[16][132];   // rules, +4 pad -> 2-way alias
  const int tid = threadIdx.x;
  const int gl = tid >> 4;          // row within this block's 16-row tile
  const int r  = tid & 15;          // rule index
  const int qrel = qrelp[0];

  // Stage all 16 rule rows: 512 f32x4, 2 per thread.
#pragma unroll
  for (int rep = 0; rep < 2; ++rep) {
    int idx = tid + rep * 256;                  // f32x4 index
    int row = idx >> 5, colv = idx & 31;
    *reinterpret_cast<f32x4*>(&sR[row][colv * 4]) =
        *reinterpret_cast<const f32x4*>(rules + (size_t)row * 128 + colv * 4);
  }
  __syncthreads();

  if ((int)blockIdx.x >= nBB) {
    const int z = (blockIdx.x - nBB) * 16 + gl;
    const float* ez = Etab + (size_t)z * 128;
    float rz = 0.f, zz = 0.f, rr = 0.f;
#pragma unroll
    for (int k = 0; k < 128; k += 4) {
      f32x4 ev = *reinterpret_cast<const f32x4*>(ez + k);
      f32x4 rv = *reinterpret_cast<const f32x4*>(&sR[r][k]);
#pragma unroll
      for (int j = 0; j < 4; ++j) {
        rz += ev[j] * rv[j];
        zz += ev[j] * ev[j];
        rr += rv[j] * rv[j];
      }
    }
    Gz[(size_t)z * 16 + r] = zz - 2.f * rz;                 // zz - 2 z.r
    if (r == qrel) G2[z] = zz + 2.f * rz + rr;              // zz + 2 z.q + qq
    const float* src = ez + r * 8;
    short8 o;
#pragma unroll
    for (int j = 0; j < 8; ++j) o[j] = (short)f2bf(src[j]);
    *reinterpret_cast<short8*>(Ebf + (size_t)z * 128 + r * 8) = o;
  } else {
    const int b = blockIdx.x * 16 + gl;
    const int hi = head[b], ti = tail[b];
    const float* hp = Etab + (size_t)hi * 128;
    const float* tp = Etab + (size_t)ti * 128;
    float hr = 0.f, tq = 0.f, hh = 0.f, tt = 0.f, rr = 0.f;
#pragma unroll
    for (int k = 0; k < 128; k += 4) {
      f32x4 hv = *reinterpret_cast<const f32x4*>(hp + k);
      f32x4 tv = *reinterpret_cast<const f32x4*>(tp + k);
      f32x4 rv = *reinterpret_cast<const f32x4*>(&sR[r][k]);
#pragma unroll
      for (int j = 0; j < 4; ++j) {
        hr += hv[j] * rv[j];
        tq += tv[j] * rv[j];
        hh += hv[j] * hv[j];
        tt += tv[j] * tv[j];
        rr += rv[j] * rv[j];
      }
    }
    C1[(size_t)b * 16 + r] = hh + rr + 2.f * hr;            // hh + rr + 2 h.r
    if (r == qrel) C2[b] = tt - 2.f * tq;                   // tt - 2 q.t
    if (r == 0) out[b] = 0.f;
    short8 oh, ot;
    const float* hsrc = hp + r * 8;
    const float* tsrc = tp + r * 8;
#pragma unroll
    for (int j = 0; j < 8; ++j) {
      oh[j] = (short)f2bf(hsrc[j]);
      ot[j] = (short)f2bf(tsrc[j]);
    }
    *reinterpret_cast<short8*>(Hbf + (size_t)b * 128 + r * 8) = oh;
    *reinterpret_cast<short8*>(Tbf + (size_t)b * 128 + r * 8) = ot;
  }
}

// Main fused kernel. Block = 32 b x 64 z (2 chunks of 32 z).
// Stage-once to LDS, single barrier, barrier-free compute from LDS.
// 4 waves: wave w -> b-half (w>>1), z-half (w&1); each owns a 16x16 MFMA tile.
// MFMA layouts (m89/m92-verified):
//   A[m=lane&15][k=quad*8+j], B[k=quad*8+j][n=lane&15], D[m=quad*4+reg][n=lane&15]
__global__ __launch_bounds__(256, 4) void ntp_main(
    const unsigned short* __restrict__ Ebf, const unsigned short* __restrict__ Hbf,
    const unsigned short* __restrict__ Tbf, const float* __restrict__ Gz,
    const float* __restrict__ G2, const float* __restrict__ C1,
    const float* __restrict__ C2, float* __restrict__ out, int Ecount) {
  // Pads: sEz row 136 shorts (272B, bank shift 4/row -> 2-way alias = free),
  // sGz row 20 f32 (80B -> 2-way), sC1 row 20 f32 (4 quad-addrs, 2-way alias).
  __shared__ __align__(16) unsigned short sEz[64][136];   // 17408 B
  __shared__ __align__(16) float sGz[64][20];             //  5120 B
  __shared__ __align__(16) float sG2[64];                 //   256 B
  __shared__ __align__(16) float sC1[32][20];             //  2560 B

  const int tid   = threadIdx.x;
  const int lane  = tid & 63, wave = tid >> 6;
  const int bhalf = wave >> 1, zhalf = wave & 1;
  const int quad  = lane >> 4, lm = lane & 15;
  const int b_base = blockIdx.x * 32;
  const int z_base = blockIdx.y * 64;

  // ---- one-shot staging (coalesced 16B/lane) ----
#pragma unroll
  for (int rep = 0; rep < 4; ++rep) {           // Ez: 64 rows x 256 B
    int c = tid + rep * 256;
    int row = c >> 4, col = c & 15;
    *reinterpret_cast<short8*>(&sEz[row][col * 8]) =
        *reinterpret_cast<const short8*>(Ebf + (size_t)(z_base + row) * 128 + col * 8);
  }
  {                                             // Gz: 64 rows x 64 B
    int row = tid >> 2, colv = tid & 3;
    *reinterpret_cast<f32x4*>(&sGz[row][colv * 4]) =
        *reinterpret_cast<const f32x4*>(Gz + (size_t)(z_base + row) * 16 + colv * 4);
  }
  if (tid < 64) sG2[tid] = G2[z_base + tid];
  if (tid < 128) {                              // C1: 32 rows x 64 B
    int row = tid >> 2, colv = tid & 3;
    *reinterpret_cast<f32x4*>(&sC1[row][colv * 4]) =
        *reinterpret_cast<const f32x4*>(&C1[(size_t)(b_base + row) * 16 + colv * 4]);
  }

  // A-fragments (H and T rows for this wave's 16 b's) register-resident.
  // Dead after the hoisted MFMA block below -> compiler reuses for grp[][].
  short8 hfrag[4], tfrag[4];
  {
    const size_t brow = (size_t)(b_base + bhalf * 16 + lm) * 128 + quad * 8;
    const unsigned short* hp = Hbf + brow;
    const unsigned short* tp = Tbf + brow;
#pragma unroll
    for (int k4 = 0; k4 < 4; ++k4) {
      hfrag[k4] = *reinterpret_cast<const short8*>(hp + k4 * 32);
      tfrag[k4] = *reinterpret_cast<const short8*>(tp + k4 * 32);
    }
  }

  // C2 for this lane's 4 b's -> registers (independent of lm).
  float c2v[4];
#pragma unroll
  for (int reg = 0; reg < 4; ++reg)
    c2v[reg] = C2[b_base + bhalf * 16 + quad * 4 + reg];

  __syncthreads();   // staging complete; no further barriers.

  const int z_loc = zhalf * 16 + lm;
  const float scale = 1.0f / (float)Ecount;

  // ---- both chunks' MFMAs hoisted up front ----
  f32x4 acc_hz[2], acc_zt[2];
#pragma unroll
  for (int c = 0; c < 2; ++c) {
    const int zr = c * 32 + z_loc;
    f32x4 ah = {0.f, 0.f, 0.f, 0.f};
    f32x4 at = {0.f, 0.f, 0.f, 0.f};
#pragma unroll
    for (int k4 = 0; k4 < 4; ++k4) {
      short8 ef = *reinterpret_cast<const short8*>(&sEz[zr][k4 * 32 + quad * 8]);
      ah = __builtin_amdgcn_mfma_f32_16x16x32_bf16(hfrag[k4], ef, ah, 0, 0, 0);
      at = __builtin_amdgcn_mfma_f32_16x16x32_bf16(tfrag[k4], ef, at, 0, 0, 0);
    }
    acc_hz[c] = ah;
    acc_zt[c] = at;
  }

  // ---- Gz pairs + G2 for BOTH chunks register-resident (read once) ----
  f32x2 grp[2][8];
  float g2v[2];
#pragma unroll
  for (int c = 0; c < 2; ++c) {
    const int zr = c * 32 + z_loc;
#pragma unroll
    for (int i = 0; i < 4; ++i) {
      f32x4 g = *reinterpret_cast<const f32x4*>(&sGz[zr][i * 4]);
      grp[c][2 * i]     = __builtin_shufflevector(g, g, 0, 1);
      grp[c][2 * i + 1] = __builtin_shufflevector(g, g, 2, 3);
    }
    g2v[c] = sG2[zr];
  }

  f32x4 acc_out = {0.f, 0.f, 0.f, 0.f};

  // ---- reg-outer / chunk-inner: sC1 row read ONCE per reg ----
#pragma unroll
  for (int reg = 0; reg < 4; ++reg) {
    const int b_loc = bhalf * 16 + quad * 4 + reg;
    f32x2 cq[8];
#pragma unroll
    for (int i = 0; i < 4; ++i) {
      f32x4 v = *reinterpret_cast<const f32x4*>(&sC1[b_loc][i * 4]);  // bcast
      cq[2 * i]     = __builtin_shufflevector(v, v, 0, 1);
      cq[2 * i + 1] = __builtin_shufflevector(v, v, 2, 3);
    }
#pragma unroll
    for (int c = 0; c < 2; ++c) {
      const float zt = acc_zt[c][reg];
      const float sq2 = g2v[c] + c2v[reg] - 2.f * zt;
      const float s2 = __builtin_amdgcn_sqrtf(__builtin_fabsf(sq2));
      const float m2hz = -2.f * acc_hz[c][reg];
      const f32x2 m2 = {m2hz, m2hz};
      f32x2 s1a = {0.f, 0.f}, s1b = {0.f, 0.f};   // 2 chains: break pk dep
#pragma unroll
      for (int p = 0; p < 8; p += 2) {
        f32x2 a0 = (cq[p] + grp[c][p]) + m2;
        f32x2 a1 = (cq[p + 1] + grp[c][p + 1]) + m2;
        f32x2 rt0, rt1;
        rt0.x = __builtin_amdgcn_sqrtf(__builtin_fabsf(a0.x));
        rt0.y = __builtin_amdgcn_sqrtf(__builtin_fabsf(a0.y));
        rt1.x = __builtin_amdgcn_sqrtf(__builtin_fabsf(a1.x));
        rt1.y = __builtin_amdgcn_sqrtf(__builtin_fabsf(a1.y));
        s1a += rt0;                               // v_pk_add_f32
        s1b += rt1;
      }
      acc_out[reg] += ((s1a.x + s1b.x) + (s1a.y + s1b.y)) * s2;  // S1*s2
    }
  }

  // Reduce over the 16 n-lanes, then one atomic per (b, z-block).
#pragma unroll
  for (int reg = 0; reg < 4; ++reg) {
    float v = acc_out[reg];
    v += __shfl_xor(v, 1, 16);
    v += __shfl_xor(v, 2, 16);
    v += __shfl_xor(v, 4, 16);
    v += __shfl_xor(v, 8, 16);
    if (lm == 0)
      atomicAdd(&out[b_base + bhalf * 16 + quad * 4 + reg], v * scale);
  }
}

extern "C" void kernel_launch(void* const* d_in, const int* in_sizes, int n_in,
                              void* d_out, int out_size, void* d_ws, size_t ws_size,
                              hipStream_t stream) {
  const int* head  = (const int*)d_in[0];
  const int* tail  = (const int*)d_in[1];
  const int* qrel  = (const int*)d_in[2];
  // d_in[3] = depth (unused at depth==1 closed form)
  const float* Etab  = (const float*)d_in[4];
  const float* rules = (const float*)d_in[5];
  const int B = in_sizes[0];
  const int E = in_sizes[4] / 128;
  float* out = (float*)d_out;

  char* ws = (char*)d_ws;
  unsigned short* Ebf = (unsigned short*)ws;                       // E*128*2 B
  unsigned short* Hbf = (unsigned short*)(ws + (size_t)E * 256);   // B*128*2 B
  unsigned short* Tbf = Hbf + (size_t)B * 128;                     // B*128*2 B
  float* Gz = (float*)(ws + (size_t)E * 256 + (size_t)B * 512);    // E*16*4 B
  float* G2 = Gz + (size_t)E * 16;                                 // E*4 B
  float* C1 = G2 + E;                                              // B*16*4 B
  float* C2 = C1 + (size_t)B * 16;                                 // B*4 B

  const int nEB = E / 16;                                          // 512
  const int nBB = B / 16;                                          // 64
  ntp_pre<<<nEB + nBB, 256, 0, stream>>>(Etab, rules, head, tail, qrel, Ebf,
                                         Hbf, Tbf, Gz, G2, C1, C2, out, nBB);
  ntp_main<<<dim3(B / 32, E / 64), 256, 0, stream>>>(Ebf, Hbf, Tbf, Gz, G2, C1,
                                                     C2, out, E);
}